// Round 1
// baseline (150.167 us; speedup 1.0000x reference)
//
#include <hip/hip_runtime.h>
#include <stdint.h>

#define B_ROWS 8192
#define H_DIM 1024
#define L_DIM 1024
#define NH 5

typedef short bf16x8 __attribute__((ext_vector_type(8)));
typedef float f32x4 __attribute__((ext_vector_type(4)));

typedef const __attribute__((address_space(1))) unsigned int* gas_uint_ptr;
typedef __attribute__((address_space(3))) unsigned int* las_uint_ptr;

__device__ __forceinline__ unsigned short f2bf(float f) {
  union { float f; unsigned int u; } v; v.f = f;
  return (unsigned short)((v.u + 0x7FFFu + ((v.u >> 16) & 1u)) >> 16);
}

__device__ __forceinline__ void load_lds16(const void* gsrc, void* ldst) {
  __builtin_amdgcn_global_load_lds((gas_uint_ptr)(uintptr_t)gsrc,
                                   (las_uint_ptr)(uintptr_t)ldst, 16, 0, 0);
}

// ---- kernel 1: bucket rows by group (LDS-aggregated atomics) ----
__global__ void k_bucket(const int* __restrict__ group, int* __restrict__ cnt,
                         int* __restrict__ rowlist) {
  __shared__ int lcnt[NH];
  __shared__ int lbase[NH];
  int t = threadIdx.x;
  if (t < NH) lcnt[t] = 0;
  __syncthreads();
  int b = blockIdx.x * 256 + t;
  int g = group[b];
  int lpos = -1;
  if (g < NH) lpos = atomicAdd(&lcnt[g], 1);
  __syncthreads();
  if (t < NH) lbase[t] = atomicAdd(&cnt[t], lcnt[t]);
  __syncthreads();
  if (g < NH) rowlist[g * B_ROWS + lbase[g] + lpos] = b;
}

// ---- kernel 2: fill group==5 rows with label value ----
__global__ void k_fill(const int* __restrict__ group, const int* __restrict__ labels,
                       float* __restrict__ out) {
  int b = blockIdx.x;
  if (group[b] != NH) return;
  float v = (float)labels[b];
  float4 vv = make_float4(v, v, v, v);
  float4* o = (float4*)(out + (size_t)b * L_DIM);
  o[threadIdx.x] = vv;  // 256 threads x 4 floats = 1024
}

// ---- kernel 3: W fp32 -> bf16 ----
__global__ void k_convw(const float* __restrict__ W, unsigned short* __restrict__ Wb) {
  int i = blockIdx.x * 256 + threadIdx.x;
  float4 w = ((const float4*)W)[i];
  ushort4 o;
  o.x = f2bf(w.x); o.y = f2bf(w.y); o.z = f2bf(w.z); o.w = f2bf(w.w);
  ((ushort4*)Wb)[i] = o;
}

// ---- kernel 4: gather selected hidden rows -> compacted bf16 matrix Hg ----
__global__ void k_gather(const float* __restrict__ hidden, const int* __restrict__ cnt,
                         const int* __restrict__ rowlist, unsigned short* __restrict__ Hg) {
  int g = blockIdx.x >> 13;
  int i = blockIdx.x & (B_ROWS - 1);
  if (i >= cnt[g]) return;
  int base = 0;
#pragma unroll
  for (int k = 0; k < NH; k++) base += (k < g) ? cnt[k] : 0;
  int b = rowlist[g * B_ROWS + i];
  float4 h = ((const float4*)(hidden + (size_t)b * H_DIM))[threadIdx.x];
  ushort4 o;
  o.x = f2bf(h.x); o.y = f2bf(h.y); o.z = f2bf(h.z); o.w = f2bf(h.w);
  ((ushort4*)(Hg + (size_t)(base + i) * H_DIM))[threadIdx.x] = o;
}

// ---- kernel 5: bucketed bf16 MFMA GEMM with scatter epilogue ----
// 128x128 tile, BK=64, 4 waves (2x2), each wave 4x4 frags of 16x16x32.
__global__ __launch_bounds__(256, 2)
void k_gemm(const unsigned short* __restrict__ Hg, const unsigned short* __restrict__ Wb,
            const float* __restrict__ bias, const int* __restrict__ cnt,
            const int* __restrict__ rowlist, float* __restrict__ out) {
  const int head = blockIdx.z;
  const int cntg = cnt[head];
  const int rowbase = blockIdx.y * 128;
  if (rowbase >= cntg) return;
  int base = 0;
#pragma unroll
  for (int k = 0; k < NH; k++) base += (k < head) ? cnt[k] : 0;
  const int n0 = blockIdx.x * 128;

  __shared__ __align__(16) unsigned short As[128 * 64];
  __shared__ __align__(16) unsigned short Bs[128 * 64];

  const int t = threadIdx.x;
  const int wave = t >> 6, lane = t & 63;
  const int quad = lane >> 4, c16 = lane & 15;
  const int wm = (wave & 1) * 64, wn = (wave >> 1) * 64;

  f32x4 acc[4][4] = {};

  const unsigned short* Wg = Wb + (size_t)head * L_DIM * H_DIM;

  for (int kt = 0; kt < H_DIM; kt += 64) {
    __syncthreads();
#pragma unroll
    for (int p = 0; p < 4; p++) {
      int c = p * 256 + t;        // 16B chunk id; lds dst = base + lane*16 (wave-uniform pattern)
      int row = c >> 3;
      int ks = (c & 7) * 8;
      int gar = base + rowbase + row;
      gar = gar < (B_ROWS - 1) ? gar : (B_ROWS - 1);  // clamp: stay inside Hg allocation
      load_lds16(Hg + (size_t)gar * H_DIM + kt + ks, As + c * 8);
      load_lds16(Wg + (size_t)(n0 + row) * H_DIM + kt + ks, Bs + c * 8);
    }
    __syncthreads();
#pragma unroll
    for (int kk = 0; kk < 64; kk += 32) {
      bf16x8 af[4], bf[4];
#pragma unroll
      for (int i = 0; i < 4; i++)
        af[i] = *(const bf16x8*)(As + (wm + i * 16 + c16) * 64 + kk + quad * 8);
#pragma unroll
      for (int j = 0; j < 4; j++)
        bf[j] = *(const bf16x8*)(Bs + (wn + j * 16 + c16) * 64 + kk + quad * 8);
#pragma unroll
      for (int i = 0; i < 4; i++)
#pragma unroll
        for (int j = 0; j < 4; j++)
          acc[i][j] = __builtin_amdgcn_mfma_f32_16x16x32_bf16(af[i], bf[j], acc[i][j], 0, 0, 0);
    }
  }

  // epilogue: C/D layout col=lane&15, row=quad*4+reg; scatter through rowlist, add bias
  const int* rl = rowlist + head * B_ROWS + rowbase;
#pragma unroll
  for (int i = 0; i < 4; i++) {
    int rloc0 = wm + i * 16 + quad * 4;
#pragma unroll
    for (int r = 0; r < 4; r++) {
      int idx = rloc0 + r;
      if (rowbase + idx < cntg) {
        int orow = rl[idx];
        float* orowp = out + (size_t)orow * L_DIM + n0;
#pragma unroll
        for (int j = 0; j < 4; j++) {
          int n = wn + j * 16 + c16;
          orowp[n] = acc[i][j][r] + bias[head * L_DIM + n0 + n];
        }
      }
    }
  }
}

extern "C" void kernel_launch(void* const* d_in, const int* in_sizes, int n_in,
                              void* d_out, int out_size, void* d_ws, size_t ws_size,
                              hipStream_t stream) {
  const float* hidden = (const float*)d_in[0];
  const float* W      = (const float*)d_in[1];
  const float* bias   = (const float*)d_in[2];
  const int* group    = (const int*)d_in[3];
  const int* labels   = (const int*)d_in[4];
  float* out = (float*)d_out;

  // ws layout: [cnt 64B][rowlist 5*8192*4B @256][Wb bf16 @262144][Hg bf16 @262144+10485760]
  char* ws = (char*)d_ws;
  int* cnt = (int*)ws;
  int* rowlist = (int*)(ws + 256);
  unsigned short* Wb = (unsigned short*)(ws + (1 << 18));
  unsigned short* Hg = (unsigned short*)(ws + (1 << 18) + (size_t)NH * L_DIM * H_DIM * 2);

  hipMemsetAsync(cnt, 0, 64, stream);
  k_bucket<<<B_ROWS / 256, 256, 0, stream>>>(group, cnt, rowlist);
  k_fill<<<B_ROWS, 256, 0, stream>>>(group, labels, out);
  k_convw<<<NH * L_DIM * H_DIM / 1024, 256, 0, stream>>>(W, Wb);
  k_gather<<<NH * B_ROWS, 256, 0, stream>>>(hidden, cnt, rowlist, Hg);
  k_gemm<<<dim3(L_DIM / 128, B_ROWS / 128, NH), 256, 0, stream>>>(Hg, Wb, bias, cnt, rowlist, out);
}

// Round 2
// 148.552 us; speedup vs baseline: 1.0109x; 1.0109x over previous
//
#include <hip/hip_runtime.h>
#include <stdint.h>

#define B_ROWS 8192
#define H_DIM 1024
#define L_DIM 1024
#define NH 5

typedef short bf16x8 __attribute__((ext_vector_type(8)));
typedef float f32x4 __attribute__((ext_vector_type(4)));

typedef const __attribute__((address_space(1))) unsigned int* gas_uint_ptr;
typedef __attribute__((address_space(3))) unsigned int* las_uint_ptr;

__device__ __forceinline__ unsigned short f2bf(float f) {
  union { float f; unsigned int u; } v; v.f = f;
  return (unsigned short)((v.u + 0x7FFFu + ((v.u >> 16) & 1u)) >> 16);
}

__device__ __forceinline__ void load_lds16(const void* gsrc, void* ldst) {
  __builtin_amdgcn_global_load_lds((gas_uint_ptr)(uintptr_t)gsrc,
                                   (las_uint_ptr)(uintptr_t)ldst, 16, 0, 0);
}

// ---- kernel 1: bucket rows by group (LDS-aggregated atomics) ----
__global__ void k_bucket(const int* __restrict__ group, int* __restrict__ cnt,
                         int* __restrict__ rowlist) {
  __shared__ int lcnt[NH];
  __shared__ int lbase[NH];
  int t = threadIdx.x;
  if (t < NH) lcnt[t] = 0;
  __syncthreads();
  int b = blockIdx.x * 256 + t;
  int g = group[b];
  int lpos = -1;
  if (g < NH) lpos = atomicAdd(&lcnt[g], 1);
  __syncthreads();
  if (t < NH) lbase[t] = atomicAdd(&cnt[t], lcnt[t]);
  __syncthreads();
  if (g < NH) rowlist[g * B_ROWS + lbase[g] + lpos] = b;
}

// ---- kernel 2: fill group==5 rows with label value ----
__global__ void k_fill(const int* __restrict__ group, const int* __restrict__ labels,
                       float* __restrict__ out) {
  int b = blockIdx.x;
  if (group[b] != NH) return;
  float v = (float)labels[b];
  float4 vv = make_float4(v, v, v, v);
  float4* o = (float4*)(out + (size_t)b * L_DIM);
  o[threadIdx.x] = vv;  // 256 threads x 4 floats = 1024
}

// ---- kernel 3: W fp32 -> bf16 ----
__global__ void k_convw(const float* __restrict__ W, unsigned short* __restrict__ Wb) {
  int i = blockIdx.x * 256 + threadIdx.x;
  float4 w = ((const float4*)W)[i];
  ushort4 o;
  o.x = f2bf(w.x); o.y = f2bf(w.y); o.z = f2bf(w.z); o.w = f2bf(w.w);
  ((ushort4*)Wb)[i] = o;
}

// ---- kernel 4: gather selected hidden rows -> compacted bf16 matrix Hg ----
__global__ void k_gather(const float* __restrict__ hidden, const int* __restrict__ cnt,
                         const int* __restrict__ rowlist, unsigned short* __restrict__ Hg) {
  int g = blockIdx.x >> 13;
  int i = blockIdx.x & (B_ROWS - 1);
  if (i >= cnt[g]) return;
  int base = 0;
#pragma unroll
  for (int k = 0; k < NH; k++) base += (k < g) ? cnt[k] : 0;
  int b = rowlist[g * B_ROWS + i];
  float4 h = ((const float4*)(hidden + (size_t)b * H_DIM))[threadIdx.x];
  ushort4 o;
  o.x = f2bf(h.x); o.y = f2bf(h.y); o.z = f2bf(h.z); o.w = f2bf(h.w);
  ((ushort4*)(Hg + (size_t)(base + i) * H_DIM))[threadIdx.x] = o;
}

// ---- kernel 5: bucketed bf16 MFMA GEMM with scatter epilogue ----
// 128x128 tile, BK=64, 4 waves (2x2), each wave 4x4 frags of 16x16x32.
// LDS layout is XOR-swizzled: chunk column cl (16B units) holds global column
// cl ^ (row&7), so ds_read_b128 fragments spread across all 32 banks
// (2 lanes/bank = free) instead of the 16-way conflict of the linear layout.
__global__ __launch_bounds__(256, 2)
void k_gemm(const unsigned short* __restrict__ Hg, const unsigned short* __restrict__ Wb,
            const float* __restrict__ bias, const int* __restrict__ cnt,
            const int* __restrict__ rowlist, float* __restrict__ out) {
  const int head = blockIdx.z;
  const int cntg = cnt[head];
  const int rowbase = blockIdx.y * 128;
  if (rowbase >= cntg) return;
  int base = 0;
#pragma unroll
  for (int k = 0; k < NH; k++) base += (k < head) ? cnt[k] : 0;
  const int n0 = blockIdx.x * 128;

  __shared__ __align__(16) unsigned short As[128 * 64];
  __shared__ __align__(16) unsigned short Bs[128 * 64];

  const int t = threadIdx.x;
  const int wave = t >> 6, lane = t & 63;
  const int quad = lane >> 4, c16 = lane & 15;
  const int wm = (wave & 1) * 64, wn = (wave >> 1) * 64;

  f32x4 acc[4][4] = {};

  const unsigned short* Wg = Wb + (size_t)head * L_DIM * H_DIM;

  for (int kt = 0; kt < H_DIM; kt += 64) {
    __syncthreads();
#pragma unroll
    for (int p = 0; p < 4; p++) {
      int c = p * 256 + t;        // LDS 16B-chunk id; lds dst = linear (wave-uniform + lane*16)
      int row = c >> 3;
      int ks = ((c & 7) ^ (row & 7)) * 8;   // XOR-swizzled source column
      int gar = base + rowbase + row;
      gar = gar < (B_ROWS - 1) ? gar : (B_ROWS - 1);  // clamp: stay inside Hg allocation
      load_lds16(Hg + (size_t)gar * H_DIM + kt + ks, As + c * 8);
      load_lds16(Wg + (size_t)(n0 + row) * H_DIM + kt + ks, Bs + c * 8);
    }
    __syncthreads();
#pragma unroll
    for (int kk = 0; kk < 64; kk += 32) {
      bf16x8 af[4], bf[4];
      const int sw = c16 & 7;               // row&7 == c16&7 for all frag rows
      const int colb = (kk >> 4) << 1;      // kk=0 -> cols 0..3, kk=32 -> cols 4..7
#pragma unroll
      for (int i = 0; i < 4; i++) {
        int row = wm + i * 16 + c16;
        int cl = (colb + quad) ^ sw;
        af[i] = *(const bf16x8*)(As + row * 64 + cl * 8);
      }
#pragma unroll
      for (int j = 0; j < 4; j++) {
        int row = wn + j * 16 + c16;
        int cl = (colb + quad) ^ sw;
        bf[j] = *(const bf16x8*)(Bs + row * 64 + cl * 8);
      }
#pragma unroll
      for (int i = 0; i < 4; i++)
#pragma unroll
        for (int j = 0; j < 4; j++)
          acc[i][j] = __builtin_amdgcn_mfma_f32_16x16x32_bf16(af[i], bf[j], acc[i][j], 0, 0, 0);
    }
  }

  // epilogue: C/D layout col=lane&15, row=quad*4+reg; scatter through rowlist, add bias
  const int* rl = rowlist + head * B_ROWS + rowbase;
#pragma unroll
  for (int i = 0; i < 4; i++) {
    int rloc0 = wm + i * 16 + quad * 4;
#pragma unroll
    for (int r = 0; r < 4; r++) {
      int idx = rloc0 + r;
      if (rowbase + idx < cntg) {
        int orow = rl[idx];
        float* orowp = out + (size_t)orow * L_DIM + n0;
#pragma unroll
        for (int j = 0; j < 4; j++) {
          int n = wn + j * 16 + c16;
          orowp[n] = acc[i][j][r] + bias[head * L_DIM + n0 + n];
        }
      }
    }
  }
}

extern "C" void kernel_launch(void* const* d_in, const int* in_sizes, int n_in,
                              void* d_out, int out_size, void* d_ws, size_t ws_size,
                              hipStream_t stream) {
  const float* hidden = (const float*)d_in[0];
  const float* W      = (const float*)d_in[1];
  const float* bias   = (const float*)d_in[2];
  const int* group    = (const int*)d_in[3];
  const int* labels   = (const int*)d_in[4];
  float* out = (float*)d_out;

  // ws layout: [cnt 64B][rowlist 5*8192*4B @256][Wb bf16 @262144][Hg bf16 @262144+10485760]
  char* ws = (char*)d_ws;
  int* cnt = (int*)ws;
  int* rowlist = (int*)(ws + 256);
  unsigned short* Wb = (unsigned short*)(ws + (1 << 18));
  unsigned short* Hg = (unsigned short*)(ws + (1 << 18) + (size_t)NH * L_DIM * H_DIM * 2);

  hipMemsetAsync(cnt, 0, 64, stream);
  k_bucket<<<B_ROWS / 256, 256, 0, stream>>>(group, cnt, rowlist);
  k_fill<<<B_ROWS, 256, 0, stream>>>(group, labels, out);
  k_convw<<<NH * L_DIM * H_DIM / 1024, 256, 0, stream>>>(W, Wb);
  k_gather<<<NH * B_ROWS, 256, 0, stream>>>(hidden, cnt, rowlist, Hg);
  k_gemm<<<dim3(L_DIM / 128, B_ROWS / 128, NH), 256, 0, stream>>>(Hg, Wb, bias, cnt, rowlist, out);
}